// Round 18
// baseline (77.257 us; speedup 1.0000x reference)
//
#include <hip/hip_runtime.h>
#include <math.h>

constexpr int E = 4;
constexpr int D = 32;
constexpr int K = 16;
constexpr int H = 32;

typedef float f32x4 __attribute__((ext_vector_type(4)));

// f32 -> nearest bf16-representable f32 (RNE, matches jax/ml_dtypes cast)
__device__ __forceinline__ float bf16r(float f) {
    unsigned int u = __float_as_uint(f);
    u = (u + 0x7FFFu + ((u >> 16) & 1u)) & 0xFFFF0000u;
    return __uint_as_float(u);
}

// ---- prep: bf16-round all weight arrays into d_ws (flat f32) -------------
__global__ void mote_prep(const float* __restrict__ r1, const float* __restrict__ b1,
                          const float* __restrict__ r2, const float* __restrict__ b2,
                          const float* __restrict__ f,  const float* __restrict__ sp,
                          const float* __restrict__ rk, const float* __restrict__ wv,
                          float* __restrict__ ws)
{
    int t = blockIdx.x * blockDim.x + threadIdx.x;
    float v;
    if      (t <   32) v = r1[t];
    else if (t <   64) v = b1[t - 32];
    else if (t <  192) v = r2[t - 64];
    else if (t <  196) v = b2[t - 192];
    else if (t < 1220) v = f [t - 196];
    else if (t < 1732) v = sp[t - 1220];
    else if (t < 2244) v = rk[t - 1732];
    else if (t < 2756) v = wv[t - 2244];
    else return;
    ws[t] = bf16r(v);
}

constexpr int LROW = 36;   // 32 payload + 4 pad f32

// ---- main: software-pipelined expert schedule to break the compute/store
//      convoy: store-issue of expert e is interleaved (8 chunks, pinned by
//      sched_barrier) with the FMA stream of expert e+1, so each wave has
//      VALU work between stores and the write pipe drains in the shadow.
//      Order: spline(prologue) -> st_sp||fourier -> st_f||rkhs ->
//      st_r||wavelet -> st_w(tail). Per-expert FP accumulation order is
//      byte-identical to r17 (absmax canary 0.01751709 must not move).
template<bool GUARD>
__global__ __launch_bounds__(256) void mote_main(
    const float* __restrict__ x_in, int B,
    const float* __restrict__ ws,
    float* __restrict__ out_emb, float* __restrict__ out_rw,
    float* __restrict__ out_mask)
{
    __shared__ float sl[4][64][LROW];

    const int tid  = threadIdx.x;
    const int wid  = tid >> 6;
    const int lane = tid & 63;
    const size_t blockbase = (size_t)blockIdx.x * 256;
    const int b = (int)blockbase + tid;
    const bool valid = !GUARD || (b < B);

    const float* rw1 = ws;
    const float* rb1 = ws + 32;
    const float* rw2 = ws + 64;
    const float* rb2 = ws + 192;
    const float* wf  = ws + 196;
    const float* wsp = ws + 1220;
    const float* wrk = ws + 1732;
    const float* wwv = ws + 2244;

    const float xb = bf16r(valid ? x_in[b] : 0.0f);

    // ---------------- router MLP in f32 + rare f64 fallback (r17) ---------
    float lv[E] = { rb2[0], rb2[1], rb2[2], rb2[3] };
#pragma unroll
    for (int j = 0; j < H; ++j) {
        const float h = fmaxf(fmaf(xb, rw1[j], rb1[j]), 0.0f);
        lv[0] = fmaf(h, rw2[j * E + 0], lv[0]);
        lv[1] = fmaf(h, rw2[j * E + 1], lv[1]);
        lv[2] = fmaf(h, rw2[j * E + 2], lv[2]);
        lv[3] = fmaf(h, rw2[j * E + 3], lv[3]);
    }
    int i1 = 0;
#pragma unroll
    for (int e = 1; e < E; ++e) if (lv[e] > lv[i1]) i1 = e;
    int i2 = (i1 == 0) ? 1 : 0;
#pragma unroll
    for (int e = 0; e < E; ++e) if (e != i1 && lv[e] > lv[i2]) i2 = e;

    float third = -3.4e38f;
#pragma unroll
    for (int e = 0; e < E; ++e)
        if (e != i1 && e != i2) third = fmaxf(third, lv[e]);
    const bool close =
        (lv[i2] - third) < 1e-3f * fmaxf(1.0f, fabsf(lv[i2]));

    if (__any((int)close)) {
        const double xd = (double)xb;
        double l0 = (double)rb2[0], l1 = (double)rb2[1];
        double l2 = (double)rb2[2], l3 = (double)rb2[3];
#pragma unroll
        for (int j = 0; j < H; ++j) {
            const double h = fmax(fma(xd, (double)rw1[j], (double)rb1[j]), 0.0);
            l0 = fma(h, (double)rw2[j * E + 0], l0);
            l1 = fma(h, (double)rw2[j * E + 1], l1);
            l2 = fma(h, (double)rw2[j * E + 2], l2);
            l3 = fma(h, (double)rw2[j * E + 3], l3);
        }
        double ld[E] = { l0, l1, l2, l3 };
        i1 = 0;
#pragma unroll
        for (int e = 1; e < E; ++e) if (ld[e] > ld[i1]) i1 = e;
        i2 = (i1 == 0) ? 1 : 0;
#pragma unroll
        for (int e = 0; e < E; ++e) if (e != i1 && ld[e] > ld[i2]) i2 = e;
#pragma unroll
        for (int e = 0; e < E; ++e) lv[e] = (float)ld[e];
    }

    const float mx = fmaxf(fmaxf(lv[0], lv[1]), fmaxf(lv[2], lv[3]));
    const float e0 = __expf(lv[0] - mx);
    const float e1 = __expf(lv[1] - mx);
    const float e2 = __expf(lv[2] - mx);
    const float e3 = __expf(lv[3] - mx);
    const float inv = 1.0f / (e0 + e1 + e2 + e3);
    float w[E] = { e0 * inv, e1 * inv, e2 * inv, e3 * inv };

    float dw[E] = {0.f, 0.f, 0.f, 0.f};
    float mk[E] = {0.f, 0.f, 0.f, 0.f};
    dw[i1] = w[i1]; dw[i2] = w[i2];
    mk[i1] = 1.0f;  mk[i2] = 1.0f;

    if (valid) {
        f32x4 vrw = { bf16r(w[0]), bf16r(w[1]), bf16r(w[2]), bf16r(w[3]) };
        __builtin_nontemporal_store(vrw,
            reinterpret_cast<f32x4*>(out_rw + (size_t)E * b));
        f32x4 vmk = { mk[0], mk[1], mk[2], mk[3] };
        __builtin_nontemporal_store(vmk,
            reinterpret_cast<f32x4*>(out_mask + (size_t)E * b));
    }

    float acc[D];
    float (*slab)[LROW] = sl[wid];
    const size_t wrowbase = blockbase + (size_t)wid * 64;
    const int r8 = lane >> 3;
    const int q  = lane & 7;

    // stage this lane's weighted, rounded acc into the wave's slab
#define STAGE(DWV)                                                             \
    do {                                                                       \
        _Pragma("unroll")                                                      \
        for (int c = 0; c < D / 4; ++c) {                                      \
            f32x4 pk = { bf16r(acc[4*c+0] * (DWV)), bf16r(acc[4*c+1] * (DWV)), \
                         bf16r(acc[4*c+2] * (DWV)), bf16r(acc[4*c+3] * (DWV)) };\
            *reinterpret_cast<f32x4*>(&slab[lane][c * 4]) = pk;                \
        }                                                                      \
    } while (0)

    // one cooperative store chunk: 8 rows x 128B contiguous, full lines
#define STORE_IT(EIDX, IT)                                                     \
    do {                                                                       \
        const int row_ = (IT) * 8 + r8;                                        \
        const f32x4 v_ = *reinterpret_cast<const f32x4*>(&slab[row_][q * 4]);  \
        if (!GUARD || (wrowbase + row_ < (size_t)B))                           \
            __builtin_nontemporal_store(v_,                                    \
                reinterpret_cast<f32x4*>(out_emb + (wrowbase + row_) * (E * D) \
                                         + (EIDX) * D + q * 4));               \
    } while (0)

    // ---- P0: spline (expert 1) prologue, un-overlapped -------------------
    {
        float phi[K];
#pragma unroll
        for (int k = 0; k < K; ++k) {
            const float knot = (float)(-2.0 + (double)k * (4.0 / 15.0));
            const float r = fmaxf(xb - knot, 0.0f);
            phi[k] = r * r * r;
        }
#pragma unroll
        for (int d = 0; d < D; ++d) acc[d] = 0.0f;
#pragma unroll
        for (int k = 0; k < K; ++k) {
            const float p = phi[k];
#pragma unroll
            for (int d = 0; d < D; ++d)
                acc[d] = fmaf(p, wsp[k * D + d], acc[d]);
        }
        STAGE(dw[1]);
    }

    // ---- F1: store spline || compute fourier (expert 0) ------------------
    // fourier: acc over k=0..31 (sins 0..15 then cos 16..31), identical
    // order to r17. cos values saved during the sin chunks.
    {
        float csave[K];
        float s1, c1, sk = 0.f, ck = 0.f;
        sincosf(xb, &s1, &c1);
#pragma unroll
        for (int d = 0; d < D; ++d) acc[d] = 0.0f;
#pragma unroll
        for (int it = 0; it < 8; ++it) {
            STORE_IT(1, it);
#pragma unroll
            for (int kk = 0; kk < 4; ++kk) {
                const int k = it * 4 + kk;           // 0..31 over all chunks
                if (k < K) {
                    if (k == 0) { sk = s1; ck = c1; }
                    else {
                        const float sn = fmaf(sk, c1,  ck * s1);
                        const float cn = fmaf(ck, c1, -sk * s1);
                        sk = sn; ck = cn;
                    }
                    csave[k] = ck;
                    const float p = sk;
#pragma unroll
                    for (int d = 0; d < D; ++d)
                        acc[d] = fmaf(p, wf[k * D + d], acc[d]);
                } else {
                    const float p = csave[k - K];
#pragma unroll
                    for (int d = 0; d < D; ++d)
                        acc[d] = fmaf(p, wf[k * D + d], acc[d]);
                }
            }
            __builtin_amdgcn_sched_barrier(0);
        }
        STAGE(dw[0]);
    }

    // ---- F2: store fourier || compute rkhs (expert 2) --------------------
    {
        float acc2[1]; (void)acc2;
        float tmp[D];
#pragma unroll
        for (int d = 0; d < D; ++d) tmp[d] = 0.0f;
#pragma unroll
        for (int it = 0; it < 8; ++it) {
            STORE_IT(0, it);
#pragma unroll
            for (int kk = 0; kk < 2; ++kk) {
                const int k = it * 2 + kk;           // 0..15
                const float knot = (float)(-2.0 + (double)k * (4.0 / 15.0));
                const float t = xb - knot;
                const float p = __expf(-4.0f * t * t);
#pragma unroll
                for (int d = 0; d < D; ++d)
                    tmp[d] = fmaf(p, wrk[k * D + d], tmp[d]);
            }
            __builtin_amdgcn_sched_barrier(0);
        }
#pragma unroll
        for (int d = 0; d < D; ++d) acc[d] = tmp[d];
        STAGE(dw[2]);
    }

    // ---- F3: store rkhs || compute wavelet (expert 3) --------------------
    {
        float tmp[D];
#pragma unroll
        for (int d = 0; d < D; ++d) tmp[d] = 0.0f;
#pragma unroll
        for (int it = 0; it < 8; ++it) {
            STORE_IT(2, it);
#pragma unroll
            for (int kk = 0; kk < 2; ++kk) {
                const int k = it * 2 + kk;           // 0..15
                const float knot = (float)(-2.0 + (double)k * (4.0 / 15.0));
                const float z  = (xb - knot) * 2.0f;
                const float z2 = z * z;
                const float p = (1.0f - z2) * __expf(-0.5f * z2);
#pragma unroll
                for (int d = 0; d < D; ++d)
                    tmp[d] = fmaf(p, wwv[k * D + d], tmp[d]);
            }
            __builtin_amdgcn_sched_barrier(0);
        }
#pragma unroll
        for (int d = 0; d < D; ++d) acc[d] = tmp[d];
        STAGE(dw[3]);
    }

    // ---- tail: store wavelet ---------------------------------------------
#pragma unroll
    for (int it = 0; it < 8; ++it) {
        STORE_IT(3, it);
    }
#undef STAGE
#undef STORE_IT
}

extern "C" void kernel_launch(void* const* d_in, const int* in_sizes, int n_in,
                              void* d_out, int out_size, void* d_ws, size_t ws_size,
                              hipStream_t stream)
{
    const int B = in_sizes[0];   // timestamp_input (B,1) f32
    const float* x   = (const float*)d_in[0];
    const float* rw1 = (const float*)d_in[1];
    const float* rb1 = (const float*)d_in[2];
    const float* rw2 = (const float*)d_in[3];
    const float* rb2 = (const float*)d_in[4];
    const float* wf  = (const float*)d_in[5];
    const float* wsp = (const float*)d_in[6];
    const float* wrk = (const float*)d_in[7];
    const float* wwv = (const float*)d_in[8];

    float* ws = (float*)d_ws;

    float* out      = (float*)d_out;
    float* out_emb  = out;
    float* out_rw   = out + (size_t)B * (E * D);
    float* out_mask = out_rw + (size_t)B * E;

    hipLaunchKernelGGL(mote_prep, dim3(11), dim3(256), 0, stream,
                       rw1, rb1, rw2, rb2, wf, wsp, wrk, wwv, ws);

    const int block = 256;
    const int grid  = (B + block - 1) / block;
    if (B % 256 == 0) {
        hipLaunchKernelGGL((mote_main<false>), dim3(grid), dim3(block), 0, stream,
                           x, B, ws, out_emb, out_rw, out_mask);
    } else {
        hipLaunchKernelGGL((mote_main<true>), dim3(grid), dim3(block), 0, stream,
                           x, B, ws, out_emb, out_rw, out_mask);
    }
}